// Round 1
// baseline (710.346 us; speedup 1.0000x reference)
//
#include <hip/hip_runtime.h>
#include <cstdint>

#define Tt 1024
#define Hh 15
#define Ii 10
#define Oo 128
#define Bb 512

__device__ __forceinline__ float sigmoidf_(float x) {
    return 1.0f / (1.0f + __expf(-x));
}
__device__ __forceinline__ float tanhf_(float x) {
    // robust for all finite x: exp(2x)->0 gives -1, ->inf gives +1
    return 1.0f - 2.0f / (__expf(2.0f * x) + 1.0f);
}

// Kernel A: the sequential recurrence.
// 64 threads/block = 1 wave; 4 batch elems per wave, 16 lanes per batch elem.
// Lane u (0..14) owns hidden unit u; h[15] replicated across lanes.
__global__ __launch_bounds__(64, 1) void gru_recur(
    const float* __restrict__ feed, const float* __restrict__ h0,
    const float* __restrict__ W_ih, const float* __restrict__ W_hh,
    const float* __restrict__ b_ih, const float* __restrict__ b_hh,
    float* __restrict__ hs)
{
    const int lane = threadIdx.x;      // 0..63
    const int g = lane >> 4;           // batch group within wave
    const int u = lane & 15;           // hidden unit (u==15 idle)
    const int uu = (u < Hh) ? u : 0;   // clamped for safe loads
    const int b = blockIdx.x * 4 + g;

    // Per-unit weight rows (same across the 4 groups -> L1 broadcast)
    float Wr[Hh], Wz[Hh], Wn[Hh];
    #pragma unroll
    for (int k = 0; k < Hh; ++k) {
        Wr[k] = W_hh[(uu         ) * Hh + k];
        Wz[k] = W_hh[(uu +     Hh) * Hh + k];
        Wn[k] = W_hh[(uu + 2 * Hh) * Hh + k];
    }

    // Time-invariant input-gate constants: gi = x@W_ih.T + b_ih, fold b_hh for r,z
    float cr = b_ih[uu]          + b_hh[uu];
    float cz = b_ih[uu + Hh]     + b_hh[uu + Hh];
    float cn = b_ih[uu + 2 * Hh];
    float bn = b_hh[uu + 2 * Hh];
    #pragma unroll
    for (int i = 0; i < Ii; ++i) {
        float x = feed[b * Ii + i];
        cr += x * W_ih[(uu         ) * Ii + i];
        cz += x * W_ih[(uu +     Hh) * Ii + i];
        cn += x * W_ih[(uu + 2 * Hh) * Ii + i];
    }

    // Replicated hidden state
    float h[Hh];
    #pragma unroll
    for (int k = 0; k < Hh; ++k) h[k] = h0[b * Hh + k];

    const int base = g << 4;
    size_t off = (size_t)b * 16 + u;

    for (int t = 0; t < Tt; ++t) {
        // 2-way split accumulators for shorter dependency chains
        float dr0 = cr, dr1 = 0.f, dz0 = cz, dz1 = 0.f, dn0 = bn, dn1 = 0.f;
        #pragma unroll
        for (int k = 0; k < Hh; k += 2) {
            dr0 += h[k] * Wr[k];
            dz0 += h[k] * Wz[k];
            dn0 += h[k] * Wn[k];
        }
        #pragma unroll
        for (int k = 1; k < Hh; k += 2) {
            dr1 += h[k] * Wr[k];
            dz1 += h[k] * Wz[k];
            dn1 += h[k] * Wn[k];
        }
        float r = sigmoidf_(dr0 + dr1);
        float z = sigmoidf_(dz0 + dz1);
        float n = tanhf_(cn + r * (dn0 + dn1));
        float hn = n + z * (h[uu] - n);   // (1-z)*n + z*h

        if (u < Hh) hs[off] = hn;
        off += (size_t)Bb * 16;

        // Re-replicate h_new across the 16-lane group
        #pragma unroll
        for (int k = 0; k < Hh; ++k) h[k] = __shfl(hn, base + k, 64);
    }
}

// Kernel B: out[p, o] = sigmoid(hs[p,:] . W_out[o,:] + b_out[o]), p = t*B+b.
// Thread owns 4 consecutive output rows' weights in registers; grid-stride over p.
__global__ __launch_bounds__(256) void gru_proj(
    const float* __restrict__ hs, const float* __restrict__ W_out,
    const float* __restrict__ b_out, float* __restrict__ out)
{
    const int q  = threadIdx.x & 31;   // which o-quad
    const int gg = threadIdx.x >> 5;   // pair slot within block (0..7)
    const int o0 = q * 4;

    float w[4][Hh];
    float bo[4];
    #pragma unroll
    for (int j = 0; j < 4; ++j) {
        bo[j] = b_out[o0 + j];
        #pragma unroll
        for (int k = 0; k < Hh; ++k) w[j][k] = W_out[(o0 + j) * Hh + k];
    }

    const int P = Tt * Bb;             // 524288 (t,b) pairs
    const int stride = gridDim.x * 8;
    for (int p = blockIdx.x * 8 + gg; p < P; p += stride) {
        const float4* hp = (const float4*)(hs + (size_t)p * 16);
        float4 A = hp[0], Bv = hp[1], C = hp[2], D = hp[3];
        float h[Hh] = {A.x, A.y, A.z, A.w, Bv.x, Bv.y, Bv.z, Bv.w,
                       C.x, C.y, C.z, C.w, D.x, D.y, D.z};
        float acc[4];
        #pragma unroll
        for (int j = 0; j < 4; ++j) {
            float s0 = bo[j], s1 = 0.f;
            #pragma unroll
            for (int k = 0; k < Hh; k += 2) s0 += h[k] * w[j][k];
            #pragma unroll
            for (int k = 1; k < Hh; k += 2) s1 += h[k] * w[j][k];
            acc[j] = sigmoidf_(s0 + s1);
        }
        float4 res = make_float4(acc[0], acc[1], acc[2], acc[3]);
        *(float4*)(out + (size_t)p * (size_t)Oo + o0) = res;
    }
}

extern "C" void kernel_launch(void* const* d_in, const int* in_sizes, int n_in,
                              void* d_out, int out_size, void* d_ws, size_t ws_size,
                              hipStream_t stream) {
    const float* feed  = (const float*)d_in[0];
    const float* h0    = (const float*)d_in[1];
    const float* W_ih  = (const float*)d_in[2];
    const float* W_hh  = (const float*)d_in[3];
    const float* b_ih  = (const float*)d_in[4];
    const float* b_hh  = (const float*)d_in[5];
    const float* W_out = (const float*)d_in[6];
    const float* b_out = (const float*)d_in[7];
    float* out = (float*)d_out;
    float* hs  = (float*)d_ws;  // T*B*16 floats = 33.5 MB, padded stride 16

    gru_recur<<<Bb / 4, 64, 0, stream>>>(feed, h0, W_ih, W_hh, b_ih, b_hh, hs);
    gru_proj<<<1024, 256, 0, stream>>>(hs, W_out, b_out, out);
}

// Round 2
// 528.194 us; speedup vs baseline: 1.3449x; 1.3449x over previous
//
#include <hip/hip_runtime.h>
#include <cstdint>

#define Tt 1024
#define Hh 15
#define Ii 10
#define Oo 128
#define Bb 512

typedef float v4f __attribute__((ext_vector_type(4)));

__device__ __forceinline__ float sigmoidf_(float x) {
    return 1.0f / (1.0f + __expf(-x));
}
__device__ __forceinline__ float tanhf_(float x) {
    return 1.0f - 2.0f / (__expf(2.0f * x) + 1.0f);
}

// DPP row-rotate of a float within the 16-lane row. j must be a literal.
#define ROT(x, j) __int_as_float(__builtin_amdgcn_update_dpp( \
    0, __float_as_int(x), 0x120 + (j), 0xF, 0xF, true))

// Kernel A: sequential recurrence. 1 wave/block, 4 batch elems/wave,
// 16 lanes (one DPP row) per batch elem; lane u owns hidden unit u.
// Cross-lane broadcast replaced by DPP row rotations (VALU-only, no LDS pipe):
//   (W h)[u] = sum_j W[u][(u +/- j) & 15] * row_ror_j(h), entries k==15 zeroed.
__global__ __launch_bounds__(64, 1) void gru_recur(
    const float* __restrict__ feed, const float* __restrict__ h0,
    const float* __restrict__ W_ih, const float* __restrict__ W_hh,
    const float* __restrict__ b_ih, const float* __restrict__ b_hh,
    float* __restrict__ hs)
{
    const int lane = threadIdx.x;      // 0..63
    const int g = lane >> 4;           // batch group = DPP row
    const int u = lane & 15;           // hidden unit (u==15 inert)
    const int uu = (u < Hh) ? u : 0;
    const int b = blockIdx.x * 4 + g;

    // Probe DPP row_ror source direction once (cannot mis-guess the ISA
    // convention this way). pr(lane0) == 1  -> src lane (i+j)&15
    //                       pr(lane0) == 15 -> src lane (i-j)&15
    int pr = __builtin_amdgcn_update_dpp(0, lane & 15, 0x121, 0xF, 0xF, true);
    int p0 = __builtin_amdgcn_readfirstlane(pr);
    const int dir = (p0 == 1) ? 1 : 15;   // 15*j == -j (mod 16)

    // Per-lane rotated weight tables; k==15 slots are 0 so the inert lane's
    // (finite) value never contributes.
    float Wr[16], Wz[16], Wn[16];
    #pragma unroll
    for (int j = 0; j < 16; ++j) {
        int k = (uu + dir * j) & 15;
        bool ok = (k < Hh);
        int kk = ok ? k : 0;
        Wr[j] = ok ? W_hh[(uu         ) * Hh + kk] : 0.0f;
        Wz[j] = ok ? W_hh[(uu +     Hh) * Hh + kk] : 0.0f;
        Wn[j] = ok ? W_hh[(uu + 2 * Hh) * Hh + kk] : 0.0f;
    }

    // Time-invariant input-gate constants (gi = x@W_ih.T + b_ih; b_hh folded
    // into r,z; b_hh n-part seeds the n-dot).
    float cr = b_ih[uu]          + b_hh[uu];
    float cz = b_ih[uu + Hh]     + b_hh[uu + Hh];
    float cn = b_ih[uu + 2 * Hh];
    float bn = b_hh[uu + 2 * Hh];
    #pragma unroll
    for (int i = 0; i < Ii; ++i) {
        float x = feed[b * Ii + i];
        cr += x * W_ih[(uu         ) * Ii + i];
        cz += x * W_ih[(uu +     Hh) * Ii + i];
        cn += x * W_ih[(uu + 2 * Hh) * Ii + i];
    }

    float hcur = (u < Hh) ? h0[b * Hh + uu] : 0.0f;
    size_t off = (size_t)b * 16 + u;

    for (int t = 0; t < Tt; ++t) {
        float hr[16];
        hr[0]  = hcur;
        hr[1]  = ROT(hcur, 1);   hr[2]  = ROT(hcur, 2);
        hr[3]  = ROT(hcur, 3);   hr[4]  = ROT(hcur, 4);
        hr[5]  = ROT(hcur, 5);   hr[6]  = ROT(hcur, 6);
        hr[7]  = ROT(hcur, 7);   hr[8]  = ROT(hcur, 8);
        hr[9]  = ROT(hcur, 9);   hr[10] = ROT(hcur, 10);
        hr[11] = ROT(hcur, 11);  hr[12] = ROT(hcur, 12);
        hr[13] = ROT(hcur, 13);  hr[14] = ROT(hcur, 14);
        hr[15] = ROT(hcur, 15);

        // 4-way split accumulators per gate (short dep chains)
        float ar[4] = {cr, 0.f, 0.f, 0.f};
        float az[4] = {cz, 0.f, 0.f, 0.f};
        float an[4] = {bn, 0.f, 0.f, 0.f};
        #pragma unroll
        for (int j = 0; j < 16; ++j) {
            ar[j & 3] += Wr[j] * hr[j];
            az[j & 3] += Wz[j] * hr[j];
            an[j & 3] += Wn[j] * hr[j];
        }
        float r = sigmoidf_((ar[0] + ar[1]) + (ar[2] + ar[3]));
        float z = sigmoidf_((az[0] + az[1]) + (az[2] + az[3]));
        float dn = (an[0] + an[1]) + (an[2] + an[3]);
        float n = tanhf_(cn + r * dn);
        float hnew = n + z * (hcur - n);

        hs[off] = hnew;            // lane15 writes pad slot (finite junk)
        off += (size_t)Bb * 16;
        hcur = hnew;
    }
}

__device__ __forceinline__ v4f ntload4(const float* p) {
    return __builtin_nontemporal_load((const v4f*)p);
}

// Kernel B: out[p,o] = sigmoid(hs[p,:] . W_out[o,:] + b_out[o]).
// 2-deep software pipeline; nontemporal streaming loads/stores.
__global__ __launch_bounds__(256) void gru_proj(
    const float* __restrict__ hs, const float* __restrict__ W_out,
    const float* __restrict__ b_out, float* __restrict__ out)
{
    const int q  = threadIdx.x & 31;   // o-quad
    const int gg = threadIdx.x >> 5;   // p-slot within block (0..7)
    const int o0 = q * 4;

    float w[4][Hh];
    float bo[4];
    #pragma unroll
    for (int j = 0; j < 4; ++j) {
        bo[j] = b_out[o0 + j];
        #pragma unroll
        for (int k = 0; k < Hh; ++k) w[j][k] = W_out[(o0 + j) * Hh + k];
    }

    const int P = Tt * Bb;
    const int stride = gridDim.x * 8;
    int p = blockIdx.x * 8 + gg;
    if (p >= P) return;

    const float* hp = hs + (size_t)p * 16;
    v4f A = ntload4(hp), B_ = ntload4(hp + 4), C = ntload4(hp + 8), D = ntload4(hp + 12);

    while (true) {
        int pn = p + stride;
        bool more = pn < P;
        const float* hpn = hs + (size_t)(more ? pn : p) * 16;
        v4f A2 = ntload4(hpn), B2 = ntload4(hpn + 4),
            C2 = ntload4(hpn + 8), D2 = ntload4(hpn + 12);

        float h[Hh] = {A.x, A.y, A.z, A.w, B_.x, B_.y, B_.z, B_.w,
                       C.x, C.y, C.z, C.w, D.x, D.y, D.z};
        float acc[4];
        #pragma unroll
        for (int j = 0; j < 4; ++j) {
            float s0 = bo[j], s1 = 0.f;
            #pragma unroll
            for (int k = 0; k < Hh; k += 2) s0 += h[k] * w[j][k];
            #pragma unroll
            for (int k = 1; k < Hh; k += 2) s1 += h[k] * w[j][k];
            acc[j] = sigmoidf_(s0 + s1);
        }
        v4f res = {acc[0], acc[1], acc[2], acc[3]};
        __builtin_nontemporal_store(res, (v4f*)(out + (size_t)p * (size_t)Oo + o0));

        if (!more) break;
        p = pn; A = A2; B_ = B2; C = C2; D = D2;
    }
}

extern "C" void kernel_launch(void* const* d_in, const int* in_sizes, int n_in,
                              void* d_out, int out_size, void* d_ws, size_t ws_size,
                              hipStream_t stream) {
    const float* feed  = (const float*)d_in[0];
    const float* h0    = (const float*)d_in[1];
    const float* W_ih  = (const float*)d_in[2];
    const float* W_hh  = (const float*)d_in[3];
    const float* b_ih  = (const float*)d_in[4];
    const float* b_hh  = (const float*)d_in[5];
    const float* W_out = (const float*)d_in[6];
    const float* b_out = (const float*)d_in[7];
    float* out = (float*)d_out;
    float* hs  = (float*)d_ws;   // [T][B][16] floats = 33.5 MB

    gru_recur<<<Bb / 4, 64, 0, stream>>>(feed, h0, W_ih, W_hh, b_ih, b_hh, hs);
    gru_proj<<<2048, 256, 0, stream>>>(hs, W_out, b_out, out);
}